// Round 8
// baseline (52.327 us; speedup 1.0000x reference)
//
#include <hip/hip_runtime.h>

#define NH 64
#define LFULL 2048
#define MH 1024
#define PI_F 3.14159265358979323846f
#define ANG_HALF 1.5339807878856412e-3f   // pi/2048
#define NREP 3   // measurement probe: repeat identical computation to expose kernel in rocprof

struct Acc { float r00r, r00i, r01r, r01i, r10r, r10i, r11r, r11i; };

#define CAUCHY_STEP(Y, AC) do {                                          \
    const float ymb = (Y) - b, ypb = (Y) + b;                            \
    const float inv1 = __builtin_amdgcn_rcpf(fmaf(a, a, ymb*ymb));       \
    const float inv2 = __builtin_amdgcn_rcpf(fmaf(a, a, ypb*ypb));       \
    const float f1 = a*inv1,   f2 = a*inv2;                              \
    const float e1 = ymb*inv1, e2 = ypb*inv2;                            \
    const float FA = f1 + f2;                                            \
    const float EB = e1 - e2;                                            \
    const float EC = e1 + e2;                                            \
    const float FD = f2 - f1;                                            \
    AC.r00r = fmaf(-p0.z, FA, fmaf(p0.w, EB, AC.r00r));                  \
    AC.r00i = fmaf(-p0.z, EC, fmaf(p0.w, FD, AC.r00i));                  \
    AC.r01r = fmaf(-p1.x, FA, fmaf(p1.y, EB, AC.r01r));                  \
    AC.r01i = fmaf(-p1.x, EC, fmaf(p1.y, FD, AC.r01i));                  \
    AC.r10r = fmaf(-p1.z, FA, fmaf(p1.w, EB, AC.r10r));                  \
    AC.r10i = fmaf(-p1.z, EC, fmaf(p1.w, FD, AC.r10i));                  \
    AC.r11r = fmaf(-v11, FA, AC.r11r);                                   \
    AC.r11i = fmaf(-v11, EC, AC.r11i);                                   \
} while (0)

__global__ __launch_bounds__(512) void hippo_ssk(
    const float* __restrict__ w_ri,
    const float* __restrict__ P_ri,
    const float* __restrict__ B_ri,
    const float* __restrict__ C_ri,
    const float* __restrict__ log_dt,
    float* __restrict__ out)
{
    __shared__ float pole[NH][12];
    __shared__ float2 Kf[MH + 1];
    __shared__ float2 bufA[MH];
    __shared__ float2 bufB[MH];

    const int h   = blockIdx.x;
    const int tid = threadIdx.x;
    const float dt = __expf(log_dt[h]);

    for (int rep = 0; rep < NREP; ++rep) {
    __syncthreads();   // protect pole[]/Kf reuse across reps

    // ---------------- Stage 1: per-pole precompute (wave 0) ----------------
    if (tid < NH) {
        const float2 w = ((const float2*)w_ri)[h*NH + tid];
        const float2 P = ((const float2*)P_ri)[h*NH + tid];
        const float2 B = ((const float2*)B_ri)[h*NH + tid];
        const float2 C = ((const float2*)C_ri)[h*NH + tid];
        float* pp = pole[tid];
        const float v00r = (B.x*C.x - B.y*C.y) * dt;
        pp[0] = w.x * dt;
        pp[1] = w.y * dt;
        pp[2] = v00r;
        pp[3] = (B.x*C.y + B.y*C.x) * dt;
        pp[4] = (B.x*P.x + B.y*P.y) * dt;
        pp[5] = (B.y*P.x - B.x*P.y) * dt;
        pp[6] = (P.x*C.x - P.y*C.y) * dt;
        pp[7] = (P.x*C.y + P.y*C.x) * dt;
        pp[8] = (P.x*P.x + P.y*P.y) * dt;
        pp[9] = 0.f; pp[10] = 0.f; pp[11] = 0.f;
        float sum = v00r;
        #pragma unroll
        for (int off = 32; off > 0; off >>= 1) sum += __shfl_down(sum, off, 64);
        if (tid == 0) Kf[MH] = make_float2(sum, 0.f);
    }
    __syncthreads();

    // ---------------- Stage 2: Cauchy kernel, pole-outer / 2-freq-inner ----------------
    {
        const int lA = tid;
        const int lB = tid + 512;
        float sA, cA, sB, cB;
        sincosf(ANG_HALF * (float)lA, &sA, &cA);
        sincosf(ANG_HALF * (float)lB, &sB, &cB);
        const float yA = 2.f * sA / cA;
        const float yB = 2.f * sB / cB;
        Acc A = {0.f,0.f,0.f,0.f,0.f,0.f,0.f,0.f};
        Acc Bq = {0.f,0.f,0.f,0.f,0.f,0.f,0.f,0.f};
        #pragma unroll 4
        for (int n = 0; n < NH; ++n) {
            const float4 p0 = *reinterpret_cast<const float4*>(&pole[n][0]);
            const float4 p1 = *reinterpret_cast<const float4*>(&pole[n][4]);
            const float v11 = pole[n][8];
            const float a = p0.x, b = p0.y;
            CAUCHY_STEP(yA, A);
            CAUCHY_STEP(yB, Bq);
        }
        #define FINISH(AC, Y, L) do {                                        \
            const float nr = AC.r01r*AC.r10r - AC.r01i*AC.r10i;              \
            const float ni = AC.r01r*AC.r10i + AC.r01i*AC.r10r;              \
            const float dr = 1.f + AC.r11r, di = AC.r11i;                    \
            const float id2 = 1.f / (dr*dr + di*di);                         \
            const float cr = (nr*dr + ni*di)*id2;                            \
            const float ci = (ni*dr - nr*di)*id2;                            \
            const float k0r = AC.r00r - cr, k0i = AC.r00i - ci;              \
            const float hy = 0.5f*(Y);                                       \
            Kf[(L)] = make_float2(k0r - k0i*hy, k0i + k0r*hy);               \
        } while (0)
        FINISH(A, yA, lA);
        FINISH(Bq, yB, lB);
        #undef FINISH
    }
    __syncthreads();

    // ---------------- Stage 3a: half-spectrum -> Z[k] ----------------
    #pragma unroll
    for (int i = 0; i < 2; ++i) {
        const int k = tid + 512*i;
        float2 Xk = Kf[k];
        if (k == 0) Xk.y = 0.f;
        float2 Xc = Kf[MH - k];
        Xc.y = -Xc.y;
        const float Er = 0.5f*(Xk.x + Xc.x), Ei = 0.5f*(Xk.y + Xc.y);
        const float Tr = 0.5f*(Xk.x - Xc.x), Ti = 0.5f*(Xk.y - Xc.y);
        const float ang = (PI_F/1024.f) * (float)k;
        float sa, ca;
        __sincosf(ang, &sa, &ca);
        const float Or = ca*Tr - sa*Ti;
        const float Oi = ca*Ti + sa*Tr;
        bufA[k] = make_float2(Er - Oi, Ei + Or);
    }
    __syncthreads();

    // ---------------- Stage 3b: 1024-pt radix-2 Stockham inverse FFT ----------------
    float2* Xb = bufA;
    float2* Yb = bufB;
    int m = 1;
    #pragma unroll
    for (int st = 0; st < 10; ++st) {
        const int jm = tid & ~(m - 1);
        const float ang = (PI_F/512.f) * (float)jm;
        float sw, cw;
        __sincosf(ang, &sw, &cw);
        const float2 c0 = Xb[tid];
        const float2 c1 = Xb[tid + 512];
        const int o0 = tid + jm;
        const float drr = c0.x - c1.x, dii = c0.y - c1.y;
        Yb[o0]     = make_float2(c0.x + c1.x, c0.y + c1.y);
        Yb[o0 + m] = make_float2(cw*drr - sw*dii, cw*dii + sw*drr);
        __syncthreads();
        float2* t = Xb; Xb = Yb; Yb = t;
        m <<= 1;
    }

    // ---------------- Stage 3c: store ----------------
    const float sc = 1.0f/1024.0f;
    float2* op2 = (float2*)(out + (size_t)h * LFULL);
    const float2 z0 = Xb[tid];
    op2[tid]       = make_float2(z0.x*sc, z0.y*sc);
    const float2 z1 = Xb[tid + 512];
    op2[tid + 512] = make_float2(z1.x*sc, z1.y*sc);
    }  // rep
}

extern "C" void kernel_launch(void* const* d_in, const int* in_sizes, int n_in,
                              void* d_out, int out_size, void* d_ws, size_t ws_size,
                              hipStream_t stream) {
    const float* w_ri   = (const float*)d_in[0];
    const float* P_ri   = (const float*)d_in[1];
    const float* B_ri   = (const float*)d_in[2];
    const float* C_ri   = (const float*)d_in[3];
    const float* log_dt = (const float*)d_in[4];
    float* out = (float*)d_out;
    const int Hn = in_sizes[4];   // 256 heads
    hippo_ssk<<<dim3(Hn), dim3(512), 0, stream>>>(w_ri, P_ri, B_ri, C_ri, log_dt, out);
}

// Round 9
// 18.987 us; speedup vs baseline: 2.7560x; 2.7560x over previous
//
#include <hip/hip_runtime.h>

#define NH 64
#define LFULL 2048
#define MH 1024
#define PI_F 3.14159265358979323846f
#define ANG_HALF 1.5339807878856412e-3f   // pi/2048

struct QS { float s1, s2, s3, s4; };   // ΣP1·U, ΣP1·V, ΣP0·U, ΣP0·V

// Per-pole per-freq contribution, quadratic single-rcp form.
// q0=(na2, m2, P0_00, P1_00), q1=(P0_01, P1_01, P0_10, P1_10), q2=(P0_11, P1_11)
#define QSTEP(Y2, Y, A00, A01, A10, A11) do {                            \
    const float dr = q0.y - (Y2);                                        \
    const float di = q0.x * (Y);                                         \
    const float t  = __builtin_amdgcn_rcpf(fmaf(dr, dr, di*di));         \
    const float U  = dr * t;                                             \
    const float V  = di * t;                                             \
    A00.s1 = fmaf(q0.w, U, A00.s1);  A00.s2 = fmaf(q0.w, V, A00.s2);     \
    A00.s3 = fmaf(q0.z, U, A00.s3);  A00.s4 = fmaf(q0.z, V, A00.s4);     \
    A01.s1 = fmaf(q1.y, U, A01.s1);  A01.s2 = fmaf(q1.y, V, A01.s2);     \
    A01.s3 = fmaf(q1.x, U, A01.s3);  A01.s4 = fmaf(q1.x, V, A01.s4);     \
    A10.s1 = fmaf(q1.w, U, A10.s1);  A10.s2 = fmaf(q1.w, V, A10.s2);     \
    A10.s3 = fmaf(q1.z, U, A10.s3);  A10.s4 = fmaf(q1.z, V, A10.s4);     \
    A11.s1 = fmaf(q2.y, U, A11.s1);  A11.s2 = fmaf(q2.y, V, A11.s2);     \
    A11.s3 = fmaf(q2.x, U, A11.s3);  A11.s4 = fmaf(q2.x, V, A11.s4);     \
} while (0)

__global__ __launch_bounds__(512) void hippo_ssk(
    const float* __restrict__ w_ri,
    const float* __restrict__ P_ri,
    const float* __restrict__ B_ri,
    const float* __restrict__ C_ri,
    const float* __restrict__ log_dt,
    float* __restrict__ out)
{
    __shared__ float pole[NH][12];   // na2, m2, P0_00, P1_00, P0_01, P1_01, P0_10, P1_10, P0_11, P1_11, pad
    __shared__ float2 Kf[MH + 1];
    __shared__ float2 bufA[MH];
    __shared__ float2 bufB[MH];

    const int h   = blockIdx.x;
    const int tid = threadIdx.x;

    // ---------------- Stage 1: per-pole quadratic coefficients (wave 0) ----------------
    // pair(v) at z=iy: [P1 + i*P0*y] / [(m2 - y^2) + i*(na2*y)]
    // na2=-2a, m2=a^2+b^2, P0=2*vr, P1=-2*(vr*a+vi*b); all v pre-scaled by dt.
    if (tid < NH) {
        const float dt = __expf(log_dt[h]);
        const float2 w = ((const float2*)w_ri)[h*NH + tid];
        const float2 P = ((const float2*)P_ri)[h*NH + tid];
        const float2 B = ((const float2*)B_ri)[h*NH + tid];
        const float2 C = ((const float2*)C_ri)[h*NH + tid];
        const float a = w.x * dt, b = w.y * dt;
        const float v00r = (B.x*C.x - B.y*C.y) * dt;
        const float v00i = (B.x*C.y + B.y*C.x) * dt;
        const float v01r = (B.x*P.x + B.y*P.y) * dt;   // B*conj(P)
        const float v01i = (B.y*P.x - B.x*P.y) * dt;
        const float v10r = (P.x*C.x - P.y*C.y) * dt;   // P*C
        const float v10i = (P.x*C.y + P.y*C.x) * dt;
        const float v11  = (P.x*P.x + P.y*P.y) * dt;   // |P|^2 (real, imag=0)
        float* pp = pole[tid];
        pp[0]  = -2.f*a;
        pp[1]  = fmaf(a, a, b*b);
        pp[2]  = 2.f*v00r;
        pp[3]  = -2.f*fmaf(v00r, a, v00i*b);
        pp[4]  = 2.f*v01r;
        pp[5]  = -2.f*fmaf(v01r, a, v01i*b);
        pp[6]  = 2.f*v10r;
        pp[7]  = -2.f*fmaf(v10r, a, v10i*b);
        pp[8]  = 2.f*v11;
        pp[9]  = -2.f*v11*a;
        pp[10] = 0.f; pp[11] = 0.f;
        // Nyquist bin (z->inf limit): Re(sum v00)
        float s = v00r;
        #pragma unroll
        for (int off = 32; off > 0; off >>= 1) s += __shfl_down(s, off, 64);
        if (tid == 0) Kf[MH] = make_float2(s, 0.f);
    }
    __syncthreads();

    // ---------------- Stage 2: Cauchy kernel, freqs (tid, tid+512) ----------------
    {
        const int lA = tid;
        const int lB = tid + 512;
        float shA, chA, shB, chB;
        __sincosf(ANG_HALF * (float)lA, &shA, &chA);
        __sincosf(ANG_HALF * (float)lB, &shB, &chB);
        const float yA = 2.f * shA * __builtin_amdgcn_rcpf(chA);
        const float yB = 2.f * shB * __builtin_amdgcn_rcpf(chB);
        const float y2A = yA*yA, y2B = yB*yB;
        QS a00A={0,0,0,0}, a01A={0,0,0,0}, a10A={0,0,0,0}, a11A={0,0,0,0};
        QS a00B={0,0,0,0}, a01B={0,0,0,0}, a10B={0,0,0,0}, a11B={0,0,0,0};
        #pragma unroll 4
        for (int n = 0; n < NH; ++n) {
            const float4 q0 = *reinterpret_cast<const float4*>(&pole[n][0]);
            const float4 q1 = *reinterpret_cast<const float4*>(&pole[n][4]);
            const float2 q2 = *reinterpret_cast<const float2*>(&pole[n][8]);
            QSTEP(y2A, yA, a00A, a01A, a10A, a11A);
            QSTEP(y2B, yB, a00B, a01B, a10B, a11B);
        }
        // Combine + Woodbury + spectral twist per freq
        #define FINISH(A00, A01, A10, A11, Y, L) do {                        \
            const float r00r = fmaf((Y), A00.s4, A00.s1);                    \
            const float r00i = fmaf((Y), A00.s3, -A00.s2);                   \
            const float r01r = fmaf((Y), A01.s4, A01.s1);                    \
            const float r01i = fmaf((Y), A01.s3, -A01.s2);                   \
            const float r10r = fmaf((Y), A10.s4, A10.s1);                    \
            const float r10i = fmaf((Y), A10.s3, -A10.s2);                   \
            const float r11r = fmaf((Y), A11.s4, A11.s1);                    \
            const float r11i = fmaf((Y), A11.s3, -A11.s2);                   \
            const float nr = r01r*r10r - r01i*r10i;                          \
            const float ni = r01r*r10i + r01i*r10r;                          \
            const float dr = 1.f + r11r, di = r11i;                          \
            const float id2 = 1.f / (dr*dr + di*di);                         \
            const float cr = (nr*dr + ni*di)*id2;                            \
            const float ci = (ni*dr - nr*di)*id2;                            \
            const float k0r = r00r - cr, k0i = r00i - ci;                    \
            const float hy = 0.5f*(Y);                                       \
            Kf[(L)] = make_float2(k0r - k0i*hy, k0i + k0r*hy);               \
        } while (0)
        FINISH(a00A, a01A, a10A, a11A, yA, lA);
        FINISH(a00B, a01B, a10B, a11B, yB, lB);
        #undef FINISH
    }
    __syncthreads();

    // ---------------- Stage 3a: half-spectrum -> Z[k] for complex IFFT ----------------
    #pragma unroll
    for (int i = 0; i < 2; ++i) {
        const int k = tid + 512*i;
        float2 Xk = Kf[k];
        if (k == 0) Xk.y = 0.f;              // bin-0 imag ignored (halfcomplex semantics)
        float2 Xc = Kf[MH - k];
        Xc.y = -Xc.y;
        const float Er = 0.5f*(Xk.x + Xc.x), Ei = 0.5f*(Xk.y + Xc.y);
        const float Tr = 0.5f*(Xk.x - Xc.x), Ti = 0.5f*(Xk.y - Xc.y);
        const float ang = (PI_F/1024.f) * (float)k;
        float sa, ca;
        __sincosf(ang, &sa, &ca);
        const float Or = ca*Tr - sa*Ti;
        const float Oi = ca*Ti + sa*Tr;
        bufA[k] = make_float2(Er - Oi, Ei + Or);
    }
    __syncthreads();

    // ---------------- Stage 3b: 1024-pt radix-2 Stockham inverse FFT ----------------
    float2* Xb = bufA;
    float2* Yb = bufB;
    int m = 1;
    #pragma unroll
    for (int st = 0; st < 10; ++st) {
        const int jm = tid & ~(m - 1);                 // j*m
        const float ang = (PI_F/512.f) * (float)jm;    // inverse FFT: +angle
        float sw, cw;
        __sincosf(ang, &sw, &cw);
        const float2 c0 = Xb[tid];
        const float2 c1 = Xb[tid + 512];
        const int o0 = tid + jm;
        const float drr = c0.x - c1.x, dii = c0.y - c1.y;
        Yb[o0]     = make_float2(c0.x + c1.x, c0.y + c1.y);
        Yb[o0 + m] = make_float2(cw*drr - sw*dii, cw*dii + sw*drr);
        __syncthreads();
        float2* t = Xb; Xb = Yb; Yb = t;
        m <<= 1;
    }

    // ---------------- Stage 3c: interleave + store ----------------
    const float sc = 1.0f/1024.0f;
    float2* op2 = (float2*)(out + (size_t)h * LFULL);
    const float2 z0 = Xb[tid];
    op2[tid]       = make_float2(z0.x*sc, z0.y*sc);
    const float2 z1 = Xb[tid + 512];
    op2[tid + 512] = make_float2(z1.x*sc, z1.y*sc);
}

extern "C" void kernel_launch(void* const* d_in, const int* in_sizes, int n_in,
                              void* d_out, int out_size, void* d_ws, size_t ws_size,
                              hipStream_t stream) {
    const float* w_ri   = (const float*)d_in[0];
    const float* P_ri   = (const float*)d_in[1];
    const float* B_ri   = (const float*)d_in[2];
    const float* C_ri   = (const float*)d_in[3];
    const float* log_dt = (const float*)d_in[4];
    float* out = (float*)d_out;
    const int Hn = in_sizes[4];   // 256 heads
    hippo_ssk<<<dim3(Hn), dim3(512), 0, stream>>>(w_ri, P_ri, B_ri, C_ri, log_dt, out);
}

// Round 10
// 17.037 us; speedup vs baseline: 3.0713x; 1.1144x over previous
//
#include <hip/hip_runtime.h>

#define NH 64
#define LFULL 2048
#define MH 1024
#define PI_F 3.14159265358979323846f
#define ANG_HALF 1.5339807878856412e-3f   // pi/2048

typedef __attribute__((ext_vector_type(2))) float f32x2;
typedef __attribute__((ext_vector_type(4))) float f32x4;

#define SV(v, i, j) __builtin_shufflevector((v), (v), (i), (j))
// acc = a*b + acc, packed 2xf32 (forced v_pk_fma_f32)
#define PK_FMA(acc, a_, b_) asm("v_pk_fma_f32 %0, %1, %2, %0" : "+v"(acc) : "v"(a_), "v"(b_))

struct QS2 { f32x2 s1, s2, s3, s4; };   // ΣP1·U, ΣP1·V, ΣP0·U, ΣP0·V (packed over 2 freqs)

__global__ __launch_bounds__(512) void hippo_ssk(
    const float* __restrict__ w_ri,
    const float* __restrict__ P_ri,
    const float* __restrict__ B_ri,
    const float* __restrict__ C_ri,
    const float* __restrict__ log_dt,
    float* __restrict__ out)
{
    // Per-pole coefficients, each duplicated into a pair for packed math:
    // [0:2)=na2, [2:4)=m2, [4:6)=P1_00, [6:8)=P0_00, [8:10)=P1_01, [10:12)=P0_01,
    // [12:14)=P1_10, [14:16)=P0_10, [16:18)=P1_11, [18:20)=P0_11
    __shared__ __attribute__((aligned(16))) float pole2[NH][20];
    __shared__ float2 Kf[MH + 1];
    __shared__ float2 bufA[MH];
    __shared__ float2 bufB[MH];

    const int h   = blockIdx.x;
    const int tid = threadIdx.x;

    // ---------------- Stage 1: per-pole quadratic coefficients (wave 0) ----------------
    // pair(v) at z=iy: [P1 + i*P0*y] / [(m2 - y^2) + i*(na2*y)]
    // na2=-2a, m2=a^2+b^2, P0=2*vr, P1=-2*(vr*a+vi*b); all v pre-scaled by dt.
    if (tid < NH) {
        const float dt = __expf(log_dt[h]);
        const float2 w = ((const float2*)w_ri)[h*NH + tid];
        const float2 P = ((const float2*)P_ri)[h*NH + tid];
        const float2 B = ((const float2*)B_ri)[h*NH + tid];
        const float2 C = ((const float2*)C_ri)[h*NH + tid];
        const float a = w.x * dt, b = w.y * dt;
        const float v00r = (B.x*C.x - B.y*C.y) * dt;
        const float v00i = (B.x*C.y + B.y*C.x) * dt;
        const float v01r = (B.x*P.x + B.y*P.y) * dt;   // B*conj(P)
        const float v01i = (B.y*P.x - B.x*P.y) * dt;
        const float v10r = (P.x*C.x - P.y*C.y) * dt;   // P*C
        const float v10i = (P.x*C.y + P.y*C.x) * dt;
        const float v11  = (P.x*P.x + P.y*P.y) * dt;   // |P|^2 (real, imag=0)
        float* pp = pole2[tid];
        const float na2 = -2.f*a;
        const float m2  = fmaf(a, a, b*b);
        const float p1_00 = -2.f*fmaf(v00r, a, v00i*b), p0_00 = 2.f*v00r;
        const float p1_01 = -2.f*fmaf(v01r, a, v01i*b), p0_01 = 2.f*v01r;
        const float p1_10 = -2.f*fmaf(v10r, a, v10i*b), p0_10 = 2.f*v10r;
        const float p1_11 = -2.f*v11*a,                 p0_11 = 2.f*v11;
        pp[0]=na2;   pp[1]=na2;   pp[2]=m2;    pp[3]=m2;
        pp[4]=p1_00; pp[5]=p1_00; pp[6]=p0_00; pp[7]=p0_00;
        pp[8]=p1_01; pp[9]=p1_01; pp[10]=p0_01; pp[11]=p0_01;
        pp[12]=p1_10; pp[13]=p1_10; pp[14]=p0_10; pp[15]=p0_10;
        pp[16]=p1_11; pp[17]=p1_11; pp[18]=p0_11; pp[19]=p0_11;
        // Nyquist bin (z->inf limit): Re(sum v00)
        float s = v00r;
        #pragma unroll
        for (int off = 32; off > 0; off >>= 1) s += __shfl_down(s, off, 64);
        if (tid == 0) Kf[MH] = make_float2(s, 0.f);
    }
    __syncthreads();

    // ---------------- Stage 2: Cauchy kernel, freqs (tid, tid+512) packed ----------------
    {
        const int lA = tid;
        const int lB = tid + 512;
        float shA, chA, shB, chB;
        __sincosf(ANG_HALF * (float)lA, &shA, &chA);
        __sincosf(ANG_HALF * (float)lB, &shB, &chB);
        const float yA = 2.f * shA * __builtin_amdgcn_rcpf(chA);
        const float yB = 2.f * shB * __builtin_amdgcn_rcpf(chB);
        f32x2 yp;  yp.x = yA;        yp.y = yB;
        f32x2 ny2; ny2.x = -yA*yA;   ny2.y = -yB*yB;
        QS2 a00 = {{0,0},{0,0},{0,0},{0,0}};
        QS2 a01 = {{0,0},{0,0},{0,0},{0,0}};
        QS2 a10 = {{0,0},{0,0},{0,0},{0,0}};
        QS2 a11 = {{0,0},{0,0},{0,0},{0,0}};
        #pragma unroll 4
        for (int n = 0; n < NH; ++n) {
            const f32x4 c0 = *reinterpret_cast<const f32x4*>(&pole2[n][0]);
            const f32x4 c1 = *reinterpret_cast<const f32x4*>(&pole2[n][4]);
            const f32x4 c2 = *reinterpret_cast<const f32x4*>(&pole2[n][8]);
            const f32x4 c3 = *reinterpret_cast<const f32x4*>(&pole2[n][12]);
            const f32x4 c4 = *reinterpret_cast<const f32x4*>(&pole2[n][16]);
            const f32x2 dr = SV(c0, 2, 3) + ny2;     // m2 - y^2
            const f32x2 di = SV(c0, 0, 1) * yp;      // na2 * y
            const f32x2 den = dr*dr + di*di;
            f32x2 t;
            t.x = __builtin_amdgcn_rcpf(den.x);
            t.y = __builtin_amdgcn_rcpf(den.y);
            const f32x2 U = dr * t;
            const f32x2 V = di * t;
            PK_FMA(a00.s1, SV(c1,0,1), U);  PK_FMA(a00.s2, SV(c1,0,1), V);
            PK_FMA(a00.s3, SV(c1,2,3), U);  PK_FMA(a00.s4, SV(c1,2,3), V);
            PK_FMA(a01.s1, SV(c2,0,1), U);  PK_FMA(a01.s2, SV(c2,0,1), V);
            PK_FMA(a01.s3, SV(c2,2,3), U);  PK_FMA(a01.s4, SV(c2,2,3), V);
            PK_FMA(a10.s1, SV(c3,0,1), U);  PK_FMA(a10.s2, SV(c3,0,1), V);
            PK_FMA(a10.s3, SV(c3,2,3), U);  PK_FMA(a10.s4, SV(c3,2,3), V);
            PK_FMA(a11.s1, SV(c4,0,1), U);  PK_FMA(a11.s2, SV(c4,0,1), V);
            PK_FMA(a11.s3, SV(c4,2,3), U);  PK_FMA(a11.s4, SV(c4,2,3), V);
        }
        // Combine (packed): r = (s1 + y*s4, y*s3 - s2)
        const f32x2 r00r = yp*a00.s4 + a00.s1;
        const f32x2 r00i = yp*a00.s3 - a00.s2;
        const f32x2 r01r = yp*a01.s4 + a01.s1;
        const f32x2 r01i = yp*a01.s3 - a01.s2;
        const f32x2 r10r = yp*a10.s4 + a10.s1;
        const f32x2 r10i = yp*a10.s3 - a10.s2;
        const f32x2 r11r = yp*a11.s4 + a11.s1;
        const f32x2 r11i = yp*a11.s3 - a11.s2;
        // Woodbury (packed): k0 = r00 - r01*r10/(1+r11)
        const f32x2 nr = r01r*r10r - r01i*r10i;
        const f32x2 ni = r01r*r10i + r01i*r10r;
        const f32x2 dw = 1.f + r11r;
        const f32x2 dv = r11i;
        f32x2 id2;
        id2.x = 1.f / (dw.x*dw.x + dv.x*dv.x);
        id2.y = 1.f / (dw.y*dw.y + dv.y*dv.y);
        const f32x2 cr = (nr*dw + ni*dv)*id2;
        const f32x2 ci = (ni*dw - nr*dv)*id2;
        const f32x2 k0r = r00r - cr;
        const f32x2 k0i = r00i - ci;
        const f32x2 hy = 0.5f*yp;               // * 2/(1+omega) = 1 + i*y/2
        Kf[lA] = make_float2(k0r.x - k0i.x*hy.x, k0i.x + k0r.x*hy.x);
        Kf[lB] = make_float2(k0r.y - k0i.y*hy.y, k0i.y + k0r.y*hy.y);
    }
    __syncthreads();

    // ---------------- Stage 3a: half-spectrum -> Z[k] for complex IFFT ----------------
    #pragma unroll
    for (int i = 0; i < 2; ++i) {
        const int k = tid + 512*i;
        float2 Xk = Kf[k];
        if (k == 0) Xk.y = 0.f;              // bin-0 imag ignored (halfcomplex semantics)
        float2 Xc = Kf[MH - k];
        Xc.y = -Xc.y;
        const float Er = 0.5f*(Xk.x + Xc.x), Ei = 0.5f*(Xk.y + Xc.y);
        const float Tr = 0.5f*(Xk.x - Xc.x), Ti = 0.5f*(Xk.y - Xc.y);
        const float ang = (PI_F/1024.f) * (float)k;
        float sa, ca;
        __sincosf(ang, &sa, &ca);
        const float Or = ca*Tr - sa*Ti;
        const float Oi = ca*Ti + sa*Tr;
        bufA[k] = make_float2(Er - Oi, Ei + Or);
    }
    __syncthreads();

    // ---------------- Stage 3b: 1024-pt radix-2 Stockham inverse FFT ----------------
    float2* Xb = bufA;
    float2* Yb = bufB;
    int m = 1;
    #pragma unroll
    for (int st = 0; st < 10; ++st) {
        const int jm = tid & ~(m - 1);                 // j*m
        const float ang = (PI_F/512.f) * (float)jm;    // inverse FFT: +angle
        float sw, cw;
        __sincosf(ang, &sw, &cw);
        const float2 c0 = Xb[tid];
        const float2 c1 = Xb[tid + 512];
        const int o0 = tid + jm;
        const float drr = c0.x - c1.x, dii = c0.y - c1.y;
        Yb[o0]     = make_float2(c0.x + c1.x, c0.y + c1.y);
        Yb[o0 + m] = make_float2(cw*drr - sw*dii, cw*dii + sw*drr);
        __syncthreads();
        float2* t = Xb; Xb = Yb; Yb = t;
        m <<= 1;
    }

    // ---------------- Stage 3c: interleave + store ----------------
    const float sc = 1.0f/1024.0f;
    float2* op2 = (float2*)(out + (size_t)h * LFULL);
    const float2 z0 = Xb[tid];
    op2[tid]       = make_float2(z0.x*sc, z0.y*sc);
    const float2 z1 = Xb[tid + 512];
    op2[tid + 512] = make_float2(z1.x*sc, z1.y*sc);
}

extern "C" void kernel_launch(void* const* d_in, const int* in_sizes, int n_in,
                              void* d_out, int out_size, void* d_ws, size_t ws_size,
                              hipStream_t stream) {
    const float* w_ri   = (const float*)d_in[0];
    const float* P_ri   = (const float*)d_in[1];
    const float* B_ri   = (const float*)d_in[2];
    const float* C_ri   = (const float*)d_in[3];
    const float* log_dt = (const float*)d_in[4];
    float* out = (float*)d_out;
    const int Hn = in_sizes[4];   // 256 heads
    hippo_ssk<<<dim3(Hn), dim3(512), 0, stream>>>(w_ri, P_ri, B_ri, C_ri, log_dt, out);
}